// Round 4
// baseline (305.472 us; speedup 1.0000x reference)
//
#include <hip/hip_runtime.h>

typedef __attribute__((ext_vector_type(8))) short s16x8;
typedef __attribute__((ext_vector_type(4))) short s16x4;
typedef __attribute__((ext_vector_type(4))) float f32x4;
typedef __attribute__((ext_vector_type(16))) float f32x16;
typedef __attribute__((ext_vector_type(2))) unsigned int u32x2;

#define DEV static __device__ __forceinline__

// async global->LDS, 16B per lane. LDS dest must be uniform base + lane*16.
DEV void gload_lds16(const void* g, void* l) {
  __builtin_amdgcn_global_load_lds(
      (const __attribute__((address_space(1))) void*)g,
      (__attribute__((address_space(3))) void*)l, 16, 0, 0);
}

DEV unsigned short f2bf(float f) {  // RNE float->bf16 (no NaN inputs here)
  unsigned int u = __float_as_uint(f);
  u = (u + 0x7fffu + ((u >> 16) & 1u)) >> 16;
  return (unsigned short)u;
}

DEV float bf2f(unsigned short u) { return __uint_as_float((unsigned)u << 16); }

DEV unsigned pk2(float lo, float hi) {  // pack 2 f32 -> 2 bf16 in one VALU op
  unsigned r;
  asm("v_cvt_pk_bf16_f32 %0, %1, %2" : "=v"(r) : "v"(lo), "v"(hi));
  return r;
}

DEV float exp2_fast(float x) {  // v_exp_f32: 2^x
  float r;
  asm("v_exp_f32 %0, %1" : "=v"(r) : "v"(x));
  return r;
}

// ---------------- fp32 -> bf16 conversion ----------------
DEV void cvt8(const float* __restrict__ in, unsigned short* __restrict__ out, int i) {
  float4 a = *(const float4*)(in + i);
  float4 b = *(const float4*)(in + i + 4);
  union { s16x8 v; unsigned short u[8]; } o;
  o.u[0] = f2bf(a.x); o.u[1] = f2bf(a.y); o.u[2] = f2bf(a.z); o.u[3] = f2bf(a.w);
  o.u[4] = f2bf(b.x); o.u[5] = f2bf(b.y); o.u[6] = f2bf(b.z); o.u[7] = f2bf(b.w);
  *(s16x8*)(out + i) = o.v;
}

__global__ __launch_bounds__(256) void k_cvt(const float* __restrict__ in,
                                             unsigned short* __restrict__ out) {
  cvt8(in, out, (blockIdx.x * 256 + threadIdx.x) * 8);
}

__global__ __launch_bounds__(256) void k_cvt4(
    const float* __restrict__ a0, const float* __restrict__ a1,
    const float* __restrict__ a2, const float* __restrict__ a3,
    unsigned short* __restrict__ o0, unsigned short* __restrict__ o1,
    unsigned short* __restrict__ o2, unsigned short* __restrict__ o3) {
  const float* in; unsigned short* out;
  switch (blockIdx.y) {
    case 0: in = a0; out = o0; break;
    case 1: in = a1; out = o1; break;
    case 2: in = a2; out = o2; break;
    default: in = a3; out = o3; break;
  }
  cvt8(in, out, (blockIdx.x * 256 + threadIdx.x) * 8);
}

// ---------------- fused QKV GEMM: C_z[M,1024] = A[M,K] * Wz[1024,K]^T + bz ----------------
// tile 128m x 64n x BK64, 256 threads = 4 waves (2m x 2n), wave-tile 64x32.
// A staged ONCE per K-step, shared by all three outputs. Outputs -> [B,H,S,dk] bf16.
__global__ __launch_bounds__(256) void k_gemm_qkv(
    const unsigned short* __restrict__ A,
    const unsigned short* __restrict__ Bq, const unsigned short* __restrict__ Bk,
    const unsigned short* __restrict__ Bv,
    const float* __restrict__ bq, const float* __restrict__ bk,
    const float* __restrict__ bv,
    unsigned short* __restrict__ oq, unsigned short* __restrict__ ok,
    unsigned short* __restrict__ ov) {
  constexpr int K = 1024;
  __shared__ unsigned short As[128 * 64];      // 16KB
  __shared__ unsigned short Bs[3][64 * 64];    // 8KB each

  const int tid = threadIdx.x;
  const int lane = tid & 63;
  const int l15 = lane & 15, g = lane >> 4;
  const int w = tid >> 6;
  const int wr = w >> 1, wc = w & 1;
  const int m0 = blockIdx.y * 128;
  const int n0 = blockIdx.x * 64;

  const int sr = tid >> 3;  // 0..31
  const int sc = tid & 7;

  const unsigned short* Bp[3] = {Bq, Bk, Bv};
  f32x4 acc[3][4][2] = {};

  for (int kt = 0; kt < K / 64; ++kt) {
#pragma unroll
    for (int i = 0; i < 4; ++i) {
      const int row = i * 32 + sr;
      gload_lds16(A + (size_t)(m0 + row) * K + kt * 64 + ((sc ^ (row & 7)) * 8),
                  (void*)(As + i * 2048 + tid * 8));
    }
#pragma unroll
    for (int z = 0; z < 3; ++z)
#pragma unroll
      for (int i = 0; i < 2; ++i) {
        const int row = i * 32 + sr;
        gload_lds16(Bp[z] + (size_t)(n0 + row) * K + kt * 64 + ((sc ^ (row & 7)) * 8),
                    (void*)(Bs[z] + i * 2048 + tid * 8));
      }
    __syncthreads();
#pragma unroll
    for (int ks = 0; ks < 2; ++ks) {
      s16x8 af[4];
#pragma unroll
      for (int mi = 0; mi < 4; ++mi) {
        const int ra = wr * 64 + mi * 16 + l15;
        af[mi] = *(const s16x8*)(As + ra * 64 + (((ks * 4 + g) ^ (ra & 7)) * 8));
      }
#pragma unroll
      for (int z = 0; z < 3; ++z) {
        s16x8 bf2[2];
#pragma unroll
        for (int nj = 0; nj < 2; ++nj) {
          const int rb = wc * 32 + nj * 16 + l15;
          bf2[nj] = *(const s16x8*)(Bs[z] + rb * 64 + (((ks * 4 + g) ^ (rb & 7)) * 8));
        }
#pragma unroll
        for (int mi = 0; mi < 4; ++mi)
#pragma unroll
          for (int nj = 0; nj < 2; ++nj)
            acc[z][mi][nj] =
                __builtin_amdgcn_mfma_f32_16x16x32_bf16(af[mi], bf2[nj], acc[z][mi][nj], 0, 0, 0);
      }
    }
    __syncthreads();
  }

  // epilogue: bias + [B,H,S,dk] store. C/D frag: col = lane&15, row = (lane>>4)*4 + reg.
  const float* biasA[3] = {bq, bk, bv};
  unsigned short* outA[3] = {oq, ok, ov};
#pragma unroll
  for (int z = 0; z < 3; ++z)
#pragma unroll
    for (int nj = 0; nj < 2; ++nj) {
      const int gcol = n0 + wc * 32 + nj * 16 + l15;
      const float bvv = biasA[z][gcol];
      const int h = gcol >> 6, d = gcol & 63;
#pragma unroll
      for (int mi = 0; mi < 4; ++mi)
#pragma unroll
        for (int r = 0; r < 4; ++r) {
          const int grow = m0 + wr * 64 + mi * 16 + g * 4 + r;
          const int bb = grow >> 11, s = grow & 2047;
          outA[z][(((size_t)(bb * 16 + h) * 2048 + s) << 6) + d] =
              f2bf(acc[z][mi][nj][r] + bvv);
        }
    }
}

// ---------------- NT GEMM (out-proj): C[M,N] = A[M,K] * W[N,K]^T + bias, fp32 out ----------------
__global__ __launch_bounds__(256) void k_gemm_o(
    const unsigned short* __restrict__ A, const unsigned short* __restrict__ Bw,
    const float* __restrict__ bias, float* __restrict__ outp) {
  constexpr int K = 1024;
  __shared__ unsigned short As[128 * 64];
  __shared__ unsigned short Bs[128 * 64];

  const int tid = threadIdx.x;
  const int lane = tid & 63;
  const int l15 = lane & 15, g = lane >> 4;
  const int w = tid >> 6;
  const int wr = w >> 1, wc = w & 1;
  const int m0 = blockIdx.y * 128;
  const int n0 = blockIdx.x * 128;

  const int sr = tid >> 3;
  const int sc = tid & 7;

  f32x4 acc[4][4] = {};

  for (int kt = 0; kt < K / 64; ++kt) {
#pragma unroll
    for (int i = 0; i < 4; ++i) {
      const int row = i * 32 + sr;
      gload_lds16(A + (size_t)(m0 + row) * K + kt * 64 + ((sc ^ (row & 7)) * 8),
                  (void*)(As + i * 2048 + tid * 8));
      gload_lds16(Bw + (size_t)(n0 + row) * K + kt * 64 + ((sc ^ (row & 7)) * 8),
                  (void*)(Bs + i * 2048 + tid * 8));
    }
    __syncthreads();
#pragma unroll
    for (int ks = 0; ks < 2; ++ks) {
      s16x8 af[4], bf[4];
#pragma unroll
      for (int i = 0; i < 4; ++i) {
        const int ra = wr * 64 + i * 16 + l15;
        af[i] = *(const s16x8*)(As + ra * 64 + (((ks * 4 + g) ^ (ra & 7)) * 8));
        const int rb = wc * 64 + i * 16 + l15;
        bf[i] = *(const s16x8*)(Bs + rb * 64 + (((ks * 4 + g) ^ (rb & 7)) * 8));
      }
#pragma unroll
      for (int i = 0; i < 4; ++i)
#pragma unroll
        for (int j = 0; j < 4; ++j)
          acc[i][j] = __builtin_amdgcn_mfma_f32_16x16x32_bf16(af[i], bf[j], acc[i][j], 0, 0, 0);
    }
    __syncthreads();
  }

#pragma unroll
  for (int j = 0; j < 4; ++j) {
    const int gcol = n0 + wc * 64 + j * 16 + l15;
    const float bv = bias[gcol];
#pragma unroll
    for (int i = 0; i < 4; ++i)
#pragma unroll
      for (int r = 0; r < 4; ++r) {
        const int grow = m0 + wr * 64 + i * 16 + g * 4 + r;
        outp[(size_t)grow * 1024 + gcol] = acc[i][j][r] + bv;
      }
  }
}

// ---------------- V transpose: [B,H,S,dk] -> [B,H,dk,S] ----------------
__global__ __launch_bounds__(256) void k_transpose(const unsigned short* __restrict__ v,
                                                   unsigned short* __restrict__ vt) {
  __shared__ unsigned short T[64 * 72];
  const int t = threadIdx.x;
  const size_t base = (size_t)(blockIdx.z * 16 + blockIdx.y) * 2048 * 64;
  const int s0 = blockIdx.x * 64;
  {
    const int srow = t >> 2, dc = (t & 3) * 16;
    const unsigned short* src = v + base + (size_t)(s0 + srow) * 64 + dc;
    *(s16x8*)(T + srow * 72 + dc) = *(const s16x8*)src;
    *(s16x8*)(T + srow * 72 + dc + 8) = *(const s16x8*)(src + 8);
  }
  __syncthreads();
  {
    const int drow = t >> 2, scc = (t & 3) * 16;
    union { s16x8 v8; unsigned short u[8]; } o0, o1;
#pragma unroll
    for (int e = 0; e < 8; ++e) o0.u[e] = T[(scc + e) * 72 + drow];
#pragma unroll
    for (int e = 0; e < 8; ++e) o1.u[e] = T[(scc + 8 + e) * 72 + drow];
    unsigned short* dst = vt + base + (size_t)drow * 2048 + s0 + scc;
    *(s16x8*)dst = o0.v8;
    *(s16x8*)(dst + 8) = o1.v8;
  }
}

// ---------------- mask reshape: mask[b][q][kv] f32 -> slab[bz][t][q][kv64] bf16 ----------------
// Pure reshape (64-kv slices are contiguous in source). Pre-scaled by 1/sqrt(dk)*log2(e).
__global__ __launch_bounds__(256) void k_maskR(const float* __restrict__ mask,
                                               unsigned short* __restrict__ mR, int b0) {
  constexpr float SC = 0.125f * 1.44269504f;
  const int tid = threadIdx.x;
  const int ql = tid >> 3, c = tid & 7;
  const int q = blockIdx.x * 32 + ql;
  const int t = blockIdx.y;
  const int bz = blockIdx.z;
  const float* src =
      mask + (size_t)(b0 + bz) * 4194304 + (size_t)q * 2048 + t * 64 + c * 8;
  float4 v0 = *(const float4*)src;
  float4 v1 = *(const float4*)(src + 4);
  union { s16x8 v; unsigned short u[8]; } o;
  o.u[0] = f2bf(v0.x * SC); o.u[1] = f2bf(v0.y * SC);
  o.u[2] = f2bf(v0.z * SC); o.u[3] = f2bf(v0.w * SC);
  o.u[4] = f2bf(v1.x * SC); o.u[5] = f2bf(v1.y * SC);
  o.u[6] = f2bf(v1.z * SC); o.u[7] = f2bf(v1.w * SC);
  *(s16x8*)(mR + (size_t)bz * 4194304 + (size_t)t * 131072 + (size_t)q * 64 + c * 8) = o.v;
}

// ---------------- flash attention, swapped-QK^T 32x32, LDS-staged mask ----------------
// grid (H=16, S/128=16, 2 batches), 256 threads = 4 waves, each wave owns 32 q-rows.
// S^T = mfma_32x32x16(K, Q): lane q = q0+w*32+(lane&31); kv = 32f+(r&3)+8*(r>>2)+4*(lane>>5).
// K [kv][d], V^T [d][kv] and mask tile [q][kv] double-buffered in LDS via global_load_lds,
// chunk^(row&7) swizzle (inverse applied on global source). Mask reads: 8x ds_read_b64,
// conflict-free (2 lanes/bank).
__global__ __launch_bounds__(256) void k_attn3(
    const unsigned short* __restrict__ q, const unsigned short* __restrict__ k,
    const unsigned short* __restrict__ vt, const unsigned short* __restrict__ mR,
    unsigned short* __restrict__ concat, int b0) {
  __shared__ unsigned short Ks[2][64 * 64];    // 8KB each
  __shared__ unsigned short Vs[2][64 * 64];    // 8KB each
  __shared__ unsigned short Ms[2][128 * 64];   // 16KB each, [q][kv]

  const int tid = threadIdx.x;
  const int lane = tid & 63;
  const int w = tid >> 6;
  const int l31 = lane & 31;
  const int hh = lane >> 5;
  const int h = blockIdx.x, qt = blockIdx.y, bz = blockIdx.z;
  const int b = b0 + bz;

  const size_t bhO = (size_t)(b * 16 + h) * (2048 * 64);
  const unsigned short* kb = k + bhO;
  const unsigned short* vb = vt + bhO;
  const int q0 = qt * 128;
  const int qc = w * 32 + l31;     // in-block q (0..127)
  const int qg = q0 + qc;          // global q row

  // Q B-fragments: qf[kd] holds Q[qg][kd*16 + hh*8 + i]
  s16x8 qf[4];
  {
    const unsigned short* qp = q + bhO + (size_t)qg * 64 + hh * 8;
#pragma unroll
    for (int kd = 0; kd < 4; ++kd) qf[kd] = *(const s16x8*)(qp + kd * 16);
  }

  const unsigned short* mtb = mR + (size_t)bz * 4194304;  // [t][q][kv64]

  float m_r = -3.0e38f, l_r = 0.f;
  f32x16 oacc[2] = {};

  const int sr = tid >> 3;  // 0..31
  const int sc = tid & 7;

#define STAGE(BUF, T_)                                                                \
  {                                                                                   \
    const int kv0s = (T_)*64;                                                         \
    _Pragma("unroll") for (int i = 0; i < 2; ++i) {                                   \
      const int row = i * 32 + sr;                                                    \
      const int sz = (sc ^ (row & 7)) * 8;                                            \
      gload_lds16(kb + (size_t)(kv0s + row) * 64 + sz,                                \
                  (void*)(Ks[BUF] + i * 2048 + tid * 8));                             \
      gload_lds16(vb + (size_t)row * 2048 + kv0s + sz,                                \
                  (void*)(Vs[BUF] + i * 2048 + tid * 8));                             \
    }                                                                                 \
    _Pragma("unroll") for (int j = 0; j < 4; ++j) {                                   \
      const int lc = j * 256 + tid;                                                   \
      const int qrow = lc >> 3, cl = lc & 7;                                          \
      gload_lds16(mtb + (size_t)(T_)*131072 + (size_t)(q0 + qrow) * 64 +              \
                      ((cl ^ (qrow & 7)) * 8),                                        \
                  (void*)(Ms[BUF] + lc * 8));                                         \
    }                                                                                 \
  }

  STAGE(0, 0)
  __syncthreads();  // compiler-emitted vmcnt(0) drains the stage

  for (int tt = 0; tt < 16; ++tt) {
#pragma unroll
    for (int half = 0; half < 2; ++half) {
      const int t = tt * 2 + half;
      if (t < 31) STAGE(half ^ 1, t + 1)

      // QK^T -> S^T [64 kv][32 q]
      f32x16 sacc[2] = {};
      __builtin_amdgcn_s_setprio(1);
#pragma unroll
      for (int f = 0; f < 2; ++f) {
        const int rk = f * 32 + l31;
        const unsigned short* Kr = Ks[half] + rk * 64;
        const int swb = rk & 7;
#pragma unroll
        for (int kd = 0; kd < 4; ++kd) {
          const s16x8 kf = *(const s16x8*)(Kr + (((kd * 2 + hh) ^ swb) * 8));
          sacc[f] = __builtin_amdgcn_mfma_f32_32x32x16_bf16(kf, qf[kd], sacc[f], 0, 0, 0);
        }
      }
      __builtin_amdgcn_s_setprio(0);

      // mask (pre-scaled bf16, [q][kv] tile) + online softmax (base-2), lane-local
      float p[32];
      float tm = -3.0e38f;
      {
        const unsigned short* Mq = Ms[half] + qc * 64 + hh * 4;
        const int sw = qc & 7;
#pragma unroll
        for (int f = 0; f < 2; ++f)
#pragma unroll
          for (int rq = 0; rq < 4; ++rq) {
            const s16x4 m4 = *(const s16x4*)(Mq + (((rq + 4 * f) ^ sw) * 8));
#pragma unroll
            for (int j = 0; j < 4; ++j) {
              const int r = 4 * rq + j;
              const float sv = sacc[f][r] * bf2f((unsigned short)m4[j]);
              p[f * 16 + r] = sv;
              tm = fmaxf(tm, sv);
            }
          }
      }
      tm = fmaxf(tm, __shfl_xor(tm, 32, 64));
      if (__any(tm > m_r + 11.5f)) {  // T13 defer-max (11.5 log2-units = 8 nats)
        const float mn = fmaxf(m_r, tm);
        const float rs = exp2_fast(m_r - mn);
        m_r = mn;
        l_r *= rs;
#pragma unroll
        for (int df = 0; df < 2; ++df)
#pragma unroll
          for (int r = 0; r < 16; ++r) oacc[df][r] *= rs;
      }
      float ps = 0.f;
#pragma unroll
      for (int n = 0; n < 32; ++n) {
        p[n] = exp2_fast(p[n] - m_r);
        ps += p[n];
      }
      ps += __shfl_xor(ps, 32, 64);
      l_r += ps;

      // P^T -> bf16 B-frags (T12) + PV: oacc[df] += V^T * P^T
#pragma unroll
      for (int ks = 0; ks < 4; ++ks) {
        const int pb = ks * 8;
        const unsigned X0 = pk2(p[pb + 0], p[pb + 1]);
        const unsigned X1 = pk2(p[pb + 2], p[pb + 3]);
        const unsigned Y0 = pk2(p[pb + 4], p[pb + 5]);
        const unsigned Y1 = pk2(p[pb + 6], p[pb + 7]);
        const u32x2 r0 = __builtin_amdgcn_permlane32_swap(X0, Y0, false, false);
        const u32x2 r1 = __builtin_amdgcn_permlane32_swap(X1, Y1, false, false);
        union { s16x8 v; unsigned u[4]; } pf;
        pf.u[0] = r0.x; pf.u[1] = r1.x; pf.u[2] = r0.y; pf.u[3] = r1.y;
        __builtin_amdgcn_s_setprio(1);
#pragma unroll
        for (int df = 0; df < 2; ++df) {
          const int rv = df * 32 + l31;
          const s16x8 vf =
              *(const s16x8*)(Vs[half] + rv * 64 + (((ks * 2 + hh) ^ (rv & 7)) * 8));
          oacc[df] = __builtin_amdgcn_mfma_f32_32x32x16_bf16(vf, pf.v, oacc[df], 0, 0, 0);
        }
        __builtin_amdgcn_s_setprio(0);
      }
      __syncthreads();  // drains vmcnt (next-tile stage) + lgkm; protects buffers
    }
  }
#undef STAGE

  // normalize + write concat [B,S,H*dk] bf16 (paired 4B stores)
  const float inv = 1.0f / l_r;
  unsigned short* cb = concat + ((size_t)b * 2048 + qg) * 1024 + h * 64;
#pragma unroll
  for (int df = 0; df < 2; ++df)
#pragma unroll
    for (int r = 0; r < 16; r += 2) {
      const int d = df * 32 + (r & 3) + 8 * (r >> 2) + 4 * hh;
      const unsigned u = (unsigned)f2bf(oacc[df][r] * inv) |
                         ((unsigned)f2bf(oacc[df][r + 1] * inv) << 16);
      *(unsigned*)(cb + d) = u;
    }
}

// ---------------- launch ----------------
extern "C" void kernel_launch(void* const* d_in, const int* in_sizes, int n_in,
                              void* d_out, int out_size, void* d_ws, size_t ws_size,
                              hipStream_t stream) {
  const float* x    = (const float*)d_in[0];
  const float* mask = (const float*)d_in[1];
  const float* Wq   = (const float*)d_in[2];
  const float* bq   = (const float*)d_in[3];
  const float* Wk   = (const float*)d_in[4];
  const float* bk   = (const float*)d_in[5];
  const float* Wv   = (const float*)d_in[6];
  const float* bv   = (const float*)d_in[7];
  const float* Wo   = (const float*)d_in[8];
  const float* bo   = (const float*)d_in[9];

  char* ws = (char*)d_ws;
  unsigned short* xb  = (unsigned short*)(ws);                        // 16 MB (x bf16; later aliased by concat)
  unsigned short* wqb = (unsigned short*)(ws + (size_t)16777216);     // 2 MB each
  unsigned short* wkb = (unsigned short*)(ws + (size_t)18874368);
  unsigned short* wvb = (unsigned short*)(ws + (size_t)20971520);
  unsigned short* wob = (unsigned short*)(ws + (size_t)23068672);
  unsigned short* qw  = (unsigned short*)(ws + (size_t)25165824);     // 16 MB each
  unsigned short* kw  = (unsigned short*)(ws + (size_t)41943040);
  unsigned short* vw  = (unsigned short*)(ws + (size_t)58720256);
  unsigned short* vtw = (unsigned short*)(ws + (size_t)75497472);     // ends at 92274688
  unsigned short* cw  = xb;   // concat aliases x_bf16 (dead after QKV GEMM)
  unsigned short* mRb = vw;   // mask slab (2 batches, 16MB) aliases vw (dead after k_transpose)

  // 1) conversions
  k_cvt<<<dim3(4096), dim3(256), 0, stream>>>(x, xb);
  k_cvt4<<<dim3(512, 4), dim3(256), 0, stream>>>(Wq, Wk, Wv, Wo, wqb, wkb, wvb, wob);
  // 2) fused QKV projections -> [B,H,S,dk] bf16
  k_gemm_qkv<<<dim3(16, 64), dim3(256), 0, stream>>>(xb, wqb, wkb, wvb, bq, bk, bv,
                                                     qw, kw, vw);
  // 3) V -> V^T [B,H,dk,S]
  k_transpose<<<dim3(32, 16, 4), dim3(256), 0, stream>>>(vw, vtw);
  // 4) attention in two batch-pair rounds (mask slab = 16MB scratch)
  k_maskR<<<dim3(64, 32, 2), dim3(256), 0, stream>>>(mask, mRb, 0);
  k_attn3<<<dim3(16, 16, 2), dim3(256), 0, stream>>>(qw, kw, vtw, mRb, cw, 0);
  k_maskR<<<dim3(64, 32, 2), dim3(256), 0, stream>>>(mask, mRb, 2);
  k_attn3<<<dim3(16, 16, 2), dim3(256), 0, stream>>>(qw, kw, vtw, mRb, cw, 2);
  // 5) output projection -> fp32 d_out
  k_gemm_o<<<dim3(8, 64), dim3(256), 0, stream>>>(cw, wob, bo, (float*)d_out);
}

// Round 5
// 243.926 us; speedup vs baseline: 1.2523x; 1.2523x over previous
//
#include <hip/hip_runtime.h>

typedef __attribute__((ext_vector_type(8))) short s16x8;
typedef __attribute__((ext_vector_type(4))) short s16x4;
typedef __attribute__((ext_vector_type(4))) float f32x4;
typedef __attribute__((ext_vector_type(16))) float f32x16;
typedef __attribute__((ext_vector_type(2))) unsigned int u32x2;

#define DEV static __device__ __forceinline__

// async global->LDS, 16B per lane. LDS dest must be uniform base + lane*16.
DEV void gload_lds16(const void* g, void* l) {
  __builtin_amdgcn_global_load_lds(
      (const __attribute__((address_space(1))) void*)g,
      (__attribute__((address_space(3))) void*)l, 16, 0, 0);
}

DEV unsigned short f2bf(float f) {  // RNE float->bf16 (no NaN inputs here)
  unsigned int u = __float_as_uint(f);
  u = (u + 0x7fffu + ((u >> 16) & 1u)) >> 16;
  return (unsigned short)u;
}

DEV float bf2f(unsigned short u) { return __uint_as_float((unsigned)u << 16); }

DEV unsigned pk2(float lo, float hi) {  // pack 2 f32 -> 2 bf16 in one VALU op
  unsigned r;
  asm("v_cvt_pk_bf16_f32 %0, %1, %2" : "=v"(r) : "v"(lo), "v"(hi));
  return r;
}

DEV float exp2_fast(float x) {  // v_exp_f32: 2^x
  float r;
  asm("v_exp_f32 %0, %1" : "=v"(r) : "v"(x));
  return r;
}

// ---------------- fp32 -> bf16 conversion (x + all four weights, one launch) ----------------
DEV void cvt8(const float* __restrict__ in, unsigned short* __restrict__ out, int i) {
  float4 a = *(const float4*)(in + i);
  float4 b = *(const float4*)(in + i + 4);
  union { s16x8 v; unsigned short u[8]; } o;
  o.u[0] = f2bf(a.x); o.u[1] = f2bf(a.y); o.u[2] = f2bf(a.z); o.u[3] = f2bf(a.w);
  o.u[4] = f2bf(b.x); o.u[5] = f2bf(b.y); o.u[6] = f2bf(b.z); o.u[7] = f2bf(b.w);
  *(s16x8*)(out + i) = o.v;
}

__global__ __launch_bounds__(256) void k_cvt_all(
    const float* __restrict__ x, const float* __restrict__ Wq,
    const float* __restrict__ Wk, const float* __restrict__ Wv,
    const float* __restrict__ Wo, unsigned short* __restrict__ xb,
    unsigned short* __restrict__ wcat) {
  const int bid = blockIdx.x;
  if (bid < 4096) {
    cvt8(x, xb, (bid * 256 + threadIdx.x) * 8);
  } else {
    const int id = bid - 4096;            // 0..2047, 512 blocks per weight
    const int sel = id >> 9;
    const float* in = (sel == 0) ? Wq : (sel == 1) ? Wk : (sel == 2) ? Wv : Wo;
    cvt8(in, wcat + sel * 1048576, ((id & 511) * 256 + threadIdx.x) * 8);
  }
}

// ---------------- concat QKV GEMM: C[M,3072] = A[M,K] * Wcat[3072,K]^T + b ----------------
// 128x128 tile, BK=64, 256 threads = 2x2 waves (64x64 wave-tile). Grid 1536 1-D with
// bijective XCD chunk swizzle (n-fastest logical order: each XCD owns 8 m-rows -> A tile
// L2-resident). z = n0>>10 selects Q/K/V. z<2 -> [B,H,S,dk] bf16; z==2 -> V^T [B,H,dk,S]
// written directly (packed 4-consecutive-s 8B stores), eliminating the transpose pass.
__global__ __launch_bounds__(256) void k_gemm_qkv(
    const unsigned short* __restrict__ A, const unsigned short* __restrict__ Bcat,
    const float* __restrict__ bq, const float* __restrict__ bk,
    const float* __restrict__ bv,
    unsigned short* __restrict__ outQK, unsigned short* __restrict__ vtw) {
  constexpr int K = 1024;
  __shared__ unsigned short As[128 * 64];
  __shared__ unsigned short Bs[128 * 64];

  const int lin = blockIdx.x;                       // 1536 blocks
  const int logical = (lin & 7) * 192 + (lin >> 3); // XCD chunk swizzle
  const int nb = logical % 24;
  const int mb = logical / 24;
  const int m0 = mb * 128;
  const int n0 = nb * 128;
  const int z = n0 >> 10;                           // 0=Q 1=K 2=V (uniform per block)

  const int tid = threadIdx.x;
  const int lane = tid & 63;
  const int l15 = lane & 15, g = lane >> 4;
  const int w = tid >> 6;
  const int wr = w >> 1, wc = w & 1;

  const int sr = tid >> 3;  // 0..31
  const int sc = tid & 7;

  f32x4 acc[4][4] = {};

  for (int kt = 0; kt < K / 64; ++kt) {
#pragma unroll
    for (int i = 0; i < 4; ++i) {
      const int row = i * 32 + sr;
      gload_lds16(A + (size_t)(m0 + row) * K + kt * 64 + ((sc ^ (row & 7)) * 8),
                  (void*)(As + i * 2048 + tid * 8));
      gload_lds16(Bcat + (size_t)(n0 + row) * K + kt * 64 + ((sc ^ (row & 7)) * 8),
                  (void*)(Bs + i * 2048 + tid * 8));
    }
    __syncthreads();
#pragma unroll
    for (int ks = 0; ks < 2; ++ks) {
      s16x8 af[4], bf[4];
#pragma unroll
      for (int i = 0; i < 4; ++i) {
        const int ra = wr * 64 + i * 16 + l15;
        af[i] = *(const s16x8*)(As + ra * 64 + (((ks * 4 + g) ^ (ra & 7)) * 8));
        const int rb = wc * 64 + i * 16 + l15;
        bf[i] = *(const s16x8*)(Bs + rb * 64 + (((ks * 4 + g) ^ (rb & 7)) * 8));
      }
#pragma unroll
      for (int i = 0; i < 4; ++i)
#pragma unroll
        for (int j = 0; j < 4; ++j)
          acc[i][j] = __builtin_amdgcn_mfma_f32_16x16x32_bf16(af[i], bf[j], acc[i][j], 0, 0, 0);
    }
    __syncthreads();
  }

  // epilogue. C/D frag: col = lane&15, row = (lane>>4)*4 + reg.
  const float* bias = (z == 0) ? bq : (z == 1) ? bk : bv;
#pragma unroll
  for (int j = 0; j < 4; ++j) {
    const int gcol = n0 + wc * 64 + j * 16 + l15;
    const int col = gcol & 1023;
    const float bvv = bias[col];
    const int h = col >> 6, d = col & 63;
#pragma unroll
    for (int i = 0; i < 4; ++i) {
      const int grow0 = m0 + wr * 64 + i * 16 + g * 4;
      const int bb = grow0 >> 11, s0 = grow0 & 2047;
      if (z < 2) {
        unsigned short* outp = outQK + (size_t)z * 8388608;
#pragma unroll
        for (int r = 0; r < 4; ++r)
          outp[(((size_t)(bb * 16 + h) * 2048 + (s0 + r)) << 6) + d] =
              f2bf(acc[i][j][r] + bvv);
      } else {
        union { s16x4 v; unsigned short u[4]; } pk;
#pragma unroll
        for (int r = 0; r < 4; ++r) pk.u[r] = f2bf(acc[i][j][r] + bvv);
        *(s16x4*)(vtw + (((size_t)(bb * 16 + h)) << 17) + (size_t)d * 2048 + s0) = pk.v;
      }
    }
  }
}

// ---------------- out-proj GEMM: C[M,1024] = A[M,K] * Wo[1024,K]^T + bo (fp32) ----------------
// 128m x 64n tile -> 1024 blocks (4/CU), XCD chunk swizzle (n-fastest logical).
__global__ __launch_bounds__(256) void k_gemm_o(
    const unsigned short* __restrict__ A, const unsigned short* __restrict__ Bw,
    const float* __restrict__ bias, float* __restrict__ outp) {
  constexpr int K = 1024;
  __shared__ unsigned short As[128 * 64];
  __shared__ unsigned short Bs[64 * 64];

  const int lin = blockIdx.x;                       // 1024 blocks
  const int logical = (lin & 7) * 128 + (lin >> 3); // XCD chunk swizzle
  const int nb = logical & 15;
  const int mb = logical >> 4;
  const int m0 = mb * 128, n0 = nb * 64;

  const int tid = threadIdx.x;
  const int lane = tid & 63;
  const int l15 = lane & 15, g = lane >> 4;
  const int w = tid >> 6;
  const int wr = w >> 1, wc = w & 1;  // wave-tile 64m x 32n

  const int sr = tid >> 3;
  const int sc = tid & 7;

  f32x4 acc[4][2] = {};

  for (int kt = 0; kt < K / 64; ++kt) {
#pragma unroll
    for (int i = 0; i < 4; ++i) {
      const int row = i * 32 + sr;
      gload_lds16(A + (size_t)(m0 + row) * K + kt * 64 + ((sc ^ (row & 7)) * 8),
                  (void*)(As + i * 2048 + tid * 8));
    }
#pragma unroll
    for (int i = 0; i < 2; ++i) {
      const int row = i * 32 + sr;
      gload_lds16(Bw + (size_t)(n0 + row) * K + kt * 64 + ((sc ^ (row & 7)) * 8),
                  (void*)(Bs + i * 2048 + tid * 8));
    }
    __syncthreads();
#pragma unroll
    for (int ks = 0; ks < 2; ++ks) {
      s16x8 af[4], bf[2];
#pragma unroll
      for (int mi = 0; mi < 4; ++mi) {
        const int ra = wr * 64 + mi * 16 + l15;
        af[mi] = *(const s16x8*)(As + ra * 64 + (((ks * 4 + g) ^ (ra & 7)) * 8));
      }
#pragma unroll
      for (int nj = 0; nj < 2; ++nj) {
        const int rb = wc * 32 + nj * 16 + l15;
        bf[nj] = *(const s16x8*)(Bs + rb * 64 + (((ks * 4 + g) ^ (rb & 7)) * 8));
      }
#pragma unroll
      for (int mi = 0; mi < 4; ++mi)
#pragma unroll
        for (int nj = 0; nj < 2; ++nj)
          acc[mi][nj] =
              __builtin_amdgcn_mfma_f32_16x16x32_bf16(af[mi], bf[nj], acc[mi][nj], 0, 0, 0);
    }
    __syncthreads();
  }

#pragma unroll
  for (int nj = 0; nj < 2; ++nj) {
    const int gcol = n0 + wc * 32 + nj * 16 + l15;
    const float bv = bias[gcol];
#pragma unroll
    for (int mi = 0; mi < 4; ++mi)
#pragma unroll
      for (int r = 0; r < 4; ++r) {
        const int grow = m0 + wr * 64 + mi * 16 + g * 4 + r;
        outp[(size_t)grow * 1024 + gcol] = acc[mi][nj][r] + bv;
      }
  }
}

// ---------------- mask reshape: mask[b][q][kv] f32 -> slab[bz][t][q][kv64] bf16 ----------------
// Pure reshape (64-kv slices are contiguous in source). Pre-scaled by 1/sqrt(dk)*log2(e).
__global__ __launch_bounds__(256) void k_maskR(const float* __restrict__ mask,
                                               unsigned short* __restrict__ mR, int b0) {
  constexpr float SC = 0.125f * 1.44269504f;
  const int tid = threadIdx.x;
  const int ql = tid >> 3, c = tid & 7;
  const int q = blockIdx.x * 32 + ql;
  const int t = blockIdx.y;
  const int bz = blockIdx.z;
  const float* src =
      mask + (size_t)(b0 + bz) * 4194304 + (size_t)q * 2048 + t * 64 + c * 8;
  float4 v0 = *(const float4*)src;
  float4 v1 = *(const float4*)(src + 4);
  union { s16x8 v; unsigned short u[8]; } o;
  o.u[0] = f2bf(v0.x * SC); o.u[1] = f2bf(v0.y * SC);
  o.u[2] = f2bf(v0.z * SC); o.u[3] = f2bf(v0.w * SC);
  o.u[4] = f2bf(v1.x * SC); o.u[5] = f2bf(v1.y * SC);
  o.u[6] = f2bf(v1.z * SC); o.u[7] = f2bf(v1.w * SC);
  *(s16x8*)(mR + (size_t)bz * 4194304 + (size_t)t * 131072 + (size_t)q * 64 + c * 8) = o.v;
}

// ---------------- flash attention, swapped-QK^T 32x32, LDS-staged mask ----------------
// grid (16,16,Z), 256 threads = 4 waves, each wave owns 32 q-rows. XCD chunk swizzle over
// the h-fastest linear id: each XCD chunk = few (b,qt) x all 16 h -> mask stripe + K/V L2 hits.
__global__ __launch_bounds__(256) void k_attn3(
    const unsigned short* __restrict__ q, const unsigned short* __restrict__ k,
    const unsigned short* __restrict__ vt, const unsigned short* __restrict__ mR,
    unsigned short* __restrict__ concat, int b0) {
  __shared__ unsigned short Ks[2][64 * 64];    // 8KB each
  __shared__ unsigned short Vs[2][64 * 64];    // 8KB each
  __shared__ unsigned short Ms[2][128 * 64];   // 16KB each, [q][kv]

  const int tid = threadIdx.x;
  const int lane = tid & 63;
  const int w = tid >> 6;
  const int l31 = lane & 31;
  const int hh = lane >> 5;

  const int lin = blockIdx.x + 16 * (blockIdx.y + 16 * blockIdx.z);
  const int q8 = (int)(gridDim.z << 8) >> 3;        // nwg/8
  const int logical = (lin & 7) * q8 + (lin >> 3);  // bijective XCD chunk swizzle
  const int h = logical & 15;
  const int qt = (logical >> 4) & 15;
  const int bz = logical >> 8;
  const int b = b0 + bz;

  const size_t bhO = (size_t)(b * 16 + h) * (2048 * 64);
  const unsigned short* kb = k + bhO;
  const unsigned short* vb = vt + bhO;
  const int q0 = qt * 128;
  const int qc = w * 32 + l31;     // in-block q (0..127)
  const int qg = q0 + qc;          // global q row

  // Q B-fragments: qf[kd] holds Q[qg][kd*16 + hh*8 + i]
  s16x8 qf[4];
  {
    const unsigned short* qp = q + bhO + (size_t)qg * 64 + hh * 8;
#pragma unroll
    for (int kd = 0; kd < 4; ++kd) qf[kd] = *(const s16x8*)(qp + kd * 16);
  }

  const unsigned short* mtb = mR + (size_t)bz * 4194304;  // [t][q][kv64]

  float m_r = -3.0e38f, l_r = 0.f;
  f32x16 oacc[2] = {};

  const int sr = tid >> 3;  // 0..31
  const int sc = tid & 7;

#define STAGE(BUF, T_)                                                                \
  {                                                                                   \
    const int kv0s = (T_)*64;                                                         \
    _Pragma("unroll") for (int i = 0; i < 2; ++i) {                                   \
      const int row = i * 32 + sr;                                                    \
      const int sz = (sc ^ (row & 7)) * 8;                                            \
      gload_lds16(kb + (size_t)(kv0s + row) * 64 + sz,                                \
                  (void*)(Ks[BUF] + i * 2048 + tid * 8));                             \
      gload_lds16(vb + (size_t)row * 2048 + kv0s + sz,                                \
                  (void*)(Vs[BUF] + i * 2048 + tid * 8));                             \
    }                                                                                 \
    _Pragma("unroll") for (int j = 0; j < 4; ++j) {                                   \
      const int lc = j * 256 + tid;                                                   \
      const int qrow = lc >> 3, cl = lc & 7;                                          \
      gload_lds16(mtb + (size_t)(T_)*131072 + (size_t)(q0 + qrow) * 64 +              \
                      ((cl ^ (qrow & 7)) * 8),                                        \
                  (void*)(Ms[BUF] + lc * 8));                                         \
    }                                                                                 \
  }

  STAGE(0, 0)
  __syncthreads();  // compiler-emitted vmcnt(0) drains the stage

  for (int tt = 0; tt < 16; ++tt) {
#pragma unroll
    for (int half = 0; half < 2; ++half) {
      const int t = tt * 2 + half;
      if (t < 31) STAGE(half ^ 1, t + 1)

      // QK^T -> S^T [64 kv][32 q]
      f32x16 sacc[2] = {};
      __builtin_amdgcn_s_setprio(1);
#pragma unroll
      for (int f = 0; f < 2; ++f) {
        const int rk = f * 32 + l31;
        const unsigned short* Kr = Ks[half] + rk * 64;
        const int swb = rk & 7;
#pragma unroll
        for (int kd = 0; kd < 4; ++kd) {
          const s16x8 kf = *(const s16x8*)(Kr + (((kd * 2 + hh) ^ swb) * 8));
          sacc[f] = __builtin_amdgcn_mfma_f32_32x32x16_bf16(kf, qf[kd], sacc[f], 0, 0, 0);
        }
      }
      __builtin_amdgcn_s_setprio(0);

      // mask (pre-scaled bf16, [q][kv] tile) + online softmax (base-2), lane-local
      float p[32];
      float tm = -3.0e38f;
      {
        const unsigned short* Mq = Ms[half] + qc * 64 + hh * 4;
        const int sw = qc & 7;
#pragma unroll
        for (int f = 0; f < 2; ++f)
#pragma unroll
          for (int rq = 0; rq < 4; ++rq) {
            const s16x4 m4 = *(const s16x4*)(Mq + (((rq + 4 * f) ^ sw) * 8));
#pragma unroll
            for (int j = 0; j < 4; ++j) {
              const int r = 4 * rq + j;
              const float sv = sacc[f][r] * bf2f((unsigned short)m4[j]);
              p[f * 16 + r] = sv;
              tm = fmaxf(tm, sv);
            }
          }
      }
      tm = fmaxf(tm, __shfl_xor(tm, 32, 64));
      if (__any(tm > m_r + 11.5f)) {  // T13 defer-max (11.5 log2-units = 8 nats)
        const float mn = fmaxf(m_r, tm);
        const float rs = exp2_fast(m_r - mn);
        m_r = mn;
        l_r *= rs;
#pragma unroll
        for (int df = 0; df < 2; ++df)
#pragma unroll
          for (int r = 0; r < 16; ++r) oacc[df][r] *= rs;
      }
      float ps = 0.f;
#pragma unroll
      for (int n = 0; n < 32; ++n) {
        p[n] = exp2_fast(p[n] - m_r);
        ps += p[n];
      }
      ps += __shfl_xor(ps, 32, 64);
      l_r += ps;

      // P^T -> bf16 B-frags (T12) + PV: oacc[df] += V^T * P^T
#pragma unroll
      for (int ks = 0; ks < 4; ++ks) {
        const int pb = ks * 8;
        const unsigned X0 = pk2(p[pb + 0], p[pb + 1]);
        const unsigned X1 = pk2(p[pb + 2], p[pb + 3]);
        const unsigned Y0 = pk2(p[pb + 4], p[pb + 5]);
        const unsigned Y1 = pk2(p[pb + 6], p[pb + 7]);
        const u32x2 r0 = __builtin_amdgcn_permlane32_swap(X0, Y0, false, false);
        const u32x2 r1 = __builtin_amdgcn_permlane32_swap(X1, Y1, false, false);
        union { s16x8 v; unsigned u[4]; } pf;
        pf.u[0] = r0.x; pf.u[1] = r1.x; pf.u[2] = r0.y; pf.u[3] = r1.y;
        __builtin_amdgcn_s_setprio(1);
#pragma unroll
        for (int df = 0; df < 2; ++df) {
          const int rv = df * 32 + l31;
          const s16x8 vf =
              *(const s16x8*)(Vs[half] + rv * 64 + (((ks * 2 + hh) ^ (rv & 7)) * 8));
          oacc[df] = __builtin_amdgcn_mfma_f32_32x32x16_bf16(vf, pf.v, oacc[df], 0, 0, 0);
        }
        __builtin_amdgcn_s_setprio(0);
      }
      __syncthreads();  // drains vmcnt (next-tile stage) + lgkm; protects buffers
    }
  }
#undef STAGE

  // normalize + write concat [B,S,H*dk] bf16 (paired 4B stores)
  const float inv = 1.0f / l_r;
  unsigned short* cb = concat + ((size_t)b * 2048 + qg) * 1024 + h * 64;
#pragma unroll
  for (int df = 0; df < 2; ++df)
#pragma unroll
    for (int r = 0; r < 16; r += 2) {
      const int d = df * 32 + (r & 3) + 8 * (r >> 2) + 4 * hh;
      const unsigned u = (unsigned)f2bf(oacc[df][r] * inv) |
                         ((unsigned)f2bf(oacc[df][r + 1] * inv) << 16);
      *(unsigned*)(cb + d) = u;
    }
}

// ---------------- launch ----------------
extern "C" void kernel_launch(void* const* d_in, const int* in_sizes, int n_in,
                              void* d_out, int out_size, void* d_ws, size_t ws_size,
                              hipStream_t stream) {
  const float* x    = (const float*)d_in[0];
  const float* mask = (const float*)d_in[1];
  const float* Wq   = (const float*)d_in[2];
  const float* bq   = (const float*)d_in[3];
  const float* Wk   = (const float*)d_in[4];
  const float* bk   = (const float*)d_in[5];
  const float* Wv   = (const float*)d_in[6];
  const float* bv   = (const float*)d_in[7];
  const float* Wo   = (const float*)d_in[8];
  const float* bo   = (const float*)d_in[9];

  char* ws = (char*)d_ws;
  unsigned short* xb    = (unsigned short*)(ws);                      // 16MB x bf16; later concat
  unsigned short* wcat  = (unsigned short*)(ws + (size_t)16777216);   // 8MB: wq|wk|wv|wo
  unsigned short* wob   = wcat + 3 * 1048576;
  unsigned short* qw    = (unsigned short*)(ws + (size_t)25165824);   // 16MB Q [B,H,S,dk]
  unsigned short* kw    = qw + 8388608;                               // 16MB K
  unsigned short* vtw   = (unsigned short*)(ws + (size_t)58720256);   // 16MB V^T [B,H,dk,S]
  unsigned short* mslab = (unsigned short*)(ws + (size_t)75497472);   // 16 or 32MB mask slab
  unsigned short* cw    = xb;  // concat aliases x_bf16 (dead after QKV GEMM)

  // 1) conversions (x + 4 weights, one launch)
  k_cvt_all<<<dim3(6144), dim3(256), 0, stream>>>(x, Wq, Wk, Wv, Wo, xb, wcat);
  // 2) concat QKV projection; V third writes V^T directly
  k_gemm_qkv<<<dim3(1536), dim3(256), 0, stream>>>(xb, wcat, bq, bk, bv, qw, vtw);
  // 3) attention (single round if ws fits a 4-batch mask slab, else two rounds)
  if (ws_size >= (size_t)75497472 + 33554432) {
    k_maskR<<<dim3(64, 32, 4), dim3(256), 0, stream>>>(mask, mslab, 0);
    k_attn3<<<dim3(16, 16, 4), dim3(256), 0, stream>>>(qw, kw, vtw, mslab, cw, 0);
  } else {
    k_maskR<<<dim3(64, 32, 2), dim3(256), 0, stream>>>(mask, mslab, 0);
    k_attn3<<<dim3(16, 16, 2), dim3(256), 0, stream>>>(qw, kw, vtw, mslab, cw, 0);
    k_maskR<<<dim3(64, 32, 2), dim3(256), 0, stream>>>(mask, mslab, 2);
    k_attn3<<<dim3(16, 16, 2), dim3(256), 0, stream>>>(qw, kw, vtw, mslab, cw, 2);
  }
  // 4) output projection -> fp32 d_out
  k_gemm_o<<<dim3(1024), dim3(256), 0, stream>>>(cw, wob, bo, (float*)d_out);
}